// Round 9
// baseline (41.852 us; speedup 1.0000x reference)
//
#include <hip/hip_runtime.h>
#include <math.h>

// Problem constants (from the reference file)
constexpr int B_   = 128;
constexpr int S_   = 2048;
constexpr int EMB_ = 128;
constexpr int HID_ = 256;
constexpr int OUT_ = 32;

constexpr int HT   = 8;         // h per block (proven R3 geometry)
constexpr int BH   = 64;        // b per block (half the batch)
constexpr int PADK = EMB_ + 4;  // 132: 16B-aligned rows, stride%32==4 -> conflict-free b128
constexpr int NBLK = 128;       // 2 dirs x 32 h-tiles x 2 b-halves

// ws layout (NO initialization required — no memset node in the graph):
//   [0]      u32 ctr    : monotone arrival counter. Works from ANY start value:
//                         among 128 consecutive returned values exactly one is
//                         ==127 (mod 128)  -> exactly one epoch bump per call.
//   [64]     u32 epoch  : bumped once per call; blocks spin on inequality vs a
//                         snapshot taken BEFORE their own arrival (poison-proof).
//   [4096..) f32 hy[2][B][HID] : fully written before any read (barrier-enforced).
constexpr size_t EPOCH_OFF = 64;
constexpr size_t HY_OFF    = 4096;

__global__ __launch_bounds__(512) void bilstm_fused(
    const int*   __restrict__ inputs,
    const float* __restrict__ weight,
    const float* __restrict__ Wxf, const float* __restrict__ bxf, const float* __restrict__ bhf,
    const float* __restrict__ Wxb, const float* __restrict__ bxb, const float* __restrict__ bhb,
    const float* __restrict__ Why, const float* __restrict__ by,
    unsigned int* __restrict__ ctr,
    unsigned int* __restrict__ epoch,
    float*        __restrict__ hy_ws,
    float*        __restrict__ out)
{
    __shared__ __align__(16) float Xs[BH][PADK];      // 33.8 KB
    __shared__ __align__(16) float Ws[3][HT][PADK];   // 12.7 KB
    __shared__ int   toks[BH];
    __shared__ __align__(16) float hv[2][HID_];       // phase 2
    __shared__ float lg[OUT_];

    const int blk   = blockIdx.x;
    const int dir   = blk >> 6;          // 64 blocks per direction
    const int ht    = (blk & 63) >> 1;   // 0..31
    const int bhalf = blk & 1;
    const int h0    = ht * HT;
    const int tid   = threadIdx.x;

    // ================= phase 1: weight-stationary gates (R3 proven) ========
    if (tid < BH)
        toks[tid] = inputs[(size_t)(bhalf * BH + tid) * S_ + (dir ? 0 : (S_ - 1))];
    __syncthreads();

    // stage X: 64 rows x 32 float4, 4 passes of 512
    #pragma unroll
    for (int p = 0; p < 4; ++p) {
        const int idx = p * 512 + tid;
        const int bl  = idx >> 5;
        const int j   = idx & 31;
        const float4 v = reinterpret_cast<const float4*>(weight + (size_t)toks[bl] * EMB_)[j];
        *reinterpret_cast<float4*>(&Xs[bl][4 * j]) = v;
    }
    // stage W: 3 gates x 8 rows x 32 float4
    {
        const float* Wx = dir ? Wxb : Wxf;
        for (int idx = tid; idx < 3 * HT * 32; idx += 512) {
            const int g   = idx >> 8;
            const int rem = idx & 255;
            const int hl  = rem >> 5;
            const int j   = rem & 31;
            const int grow = (g == 0) ? 0 : ((g == 1) ? 2 : 3);  // i, g, o rows
            const float4 v = reinterpret_cast<const float4*>(
                Wx + (size_t)(grow * HID_ + h0 + hl) * EMB_)[j];
            *reinterpret_cast<float4*>(&Ws[g][hl][4 * j]) = v;
        }
    }
    __syncthreads();

    // gates: thread = (hl, bg); hy -> workspace (2 KB/block)
    {
        const int hl = tid & (HT - 1);
        const int bg = tid >> 3;
        const int h  = h0 + hl;
        const float* bx = dir ? bxb : bxf;
        const float* bh = dir ? bhb : bhf;
        float gi = bx[h]            + bh[h];
        float gg = bx[2 * HID_ + h] + bh[2 * HID_ + h];
        float go = bx[3 * HID_ + h] + bh[3 * HID_ + h];

        #pragma unroll 8
        for (int k4 = 0; k4 < EMB_ / 4; ++k4) {
            const float4 x  = *reinterpret_cast<const float4*>(&Xs[bg][4 * k4]);
            const float4 wi = *reinterpret_cast<const float4*>(&Ws[0][hl][4 * k4]);
            const float4 wg = *reinterpret_cast<const float4*>(&Ws[1][hl][4 * k4]);
            const float4 wo = *reinterpret_cast<const float4*>(&Ws[2][hl][4 * k4]);
            gi = fmaf(x.x, wi.x, fmaf(x.y, wi.y, fmaf(x.z, wi.z, fmaf(x.w, wi.w, gi))));
            gg = fmaf(x.x, wg.x, fmaf(x.y, wg.y, fmaf(x.z, wg.z, fmaf(x.w, wg.w, gg))));
            go = fmaf(x.x, wo.x, fmaf(x.y, wo.y, fmaf(x.z, wo.z, fmaf(x.w, wo.w, go))));
        }
        const float si = 1.0f / (1.0f + expf(-gi));
        const float so = 1.0f / (1.0f + expf(-go));
        hy_ws[((size_t)dir * B_ + (bhalf * BH + bg)) * HID_ + h] =
            so * tanhf(si * tanhf(gg));
    }

    // ================= grid barrier: epoch spin, zero initialization =======
    // All 128 blocks (512 thr, ~50 KB LDS) are co-resident on 256 CUs -> safe.
    __threadfence();     // release this block's hy stores
    __syncthreads();     // all threads' stores+fences done before signaling
    if (tid == 0) {
        const unsigned int e0 = atomicAdd(epoch, 0u);   // snapshot BEFORE arrival
        __threadfence();
        const unsigned int old = atomicAdd(ctr, 1u);
        if ((old & (NBLK - 1u)) == (NBLK - 1u)) {       // exactly once per call
            __threadfence();
            atomicAdd(epoch, 1u);
        }
        while (atomicAdd(epoch, 0u) == e0)
            __builtin_amdgcn_s_sleep(2);
        __threadfence();  // acquire before cross-XCD hy reads
    }
    __syncthreads();

    // ================= phase 2: logits + log-softmax for batch row `blk` ===
    {
        const int d = tid >> 8;          // 0,1
        const int h = tid & 255;
        hv[d][h] = hy_ws[((size_t)d * B_ + blk) * HID_ + h];   // 2x1KB coalesced
    }
    __syncthreads();

    const int wave = tid >> 6;
    const int lane = tid & 63;
    #pragma unroll
    for (int i = 0; i < 4; ++i) {
        const int o = wave + 8 * i;
        const float4 wv = reinterpret_cast<const float4*>(Why + (size_t)o * HID_)[lane];
        const float4 a0 = *reinterpret_cast<const float4*>(&hv[0][4 * lane]);
        const float4 a1 = *reinterpret_cast<const float4*>(&hv[1][4 * lane]);
        float p = wv.x * (a0.x + a1.x) + wv.y * (a0.y + a1.y)
                + wv.z * (a0.z + a1.z) + wv.w * (a0.w + a1.w);
        #pragma unroll
        for (int off = 32; off; off >>= 1) p += __shfl_xor(p, off);
        if (lane == 0) lg[o] = p + by[o];
    }
    __syncthreads();

    if (tid < OUT_) {
        const float v = lg[tid];
        float m = v;
        #pragma unroll
        for (int off = 16; off; off >>= 1) m = fmaxf(m, __shfl_xor(m, off));
        float s = expf(v - m);
        #pragma unroll
        for (int off = 16; off; off >>= 1) s += __shfl_xor(s, off);
        out[(size_t)blk * OUT_ + tid] = v - m - logf(s);
    }
}

extern "C" void kernel_launch(void* const* d_in, const int* in_sizes, int n_in,
                              void* d_out, int out_size, void* d_ws, size_t ws_size,
                              hipStream_t stream) {
    // setup_inputs() order:
    // 0 inputs [B,S] int32      1 weight [VOCAB,EMB] f32
    // 2 Wxf [1024,128]  3 bxf [1024]  4 Whf (dead)  5 bhf [1024]
    // 6 Wxb [1024,128]  7 bxb [1024]  8 Whb (dead)  9 bhb [1024]
    // 10 Why [32,256]   11 by [32]
    const int*   inputs = (const int*)  d_in[0];
    const float* weight = (const float*)d_in[1];
    const float* Wxf    = (const float*)d_in[2];
    const float* bxf    = (const float*)d_in[3];
    const float* bhf    = (const float*)d_in[5];
    const float* Wxb    = (const float*)d_in[6];
    const float* bxb    = (const float*)d_in[7];
    const float* bhb    = (const float*)d_in[9];
    const float* Why    = (const float*)d_in[10];
    const float* by     = (const float*)d_in[11];
    float* out = (float*)d_out;

    unsigned int* ctr   = (unsigned int*)d_ws;
    unsigned int* epoch = (unsigned int*)((char*)d_ws + EPOCH_OFF);
    float*        hy_ws = (float*)((char*)d_ws + HY_OFF);

    // Single dispatch. No memset node (the epoch barrier needs no init).
    bilstm_fused<<<NBLK, 512, 0, stream>>>(inputs, weight,
                                           Wxf, bxf, bhf,
                                           Wxb, bxb, bhb,
                                           Why, by, ctr, epoch, hy_ws, out);
}

// Round 10
// 19.939 us; speedup vs baseline: 2.0990x; 2.0990x over previous
//
#include <hip/hip_runtime.h>
#include <math.h>

// Problem constants (from the reference file)
constexpr int B_   = 128;
constexpr int S_   = 2048;
constexpr int EMB_ = 128;
constexpr int HID_ = 256;
constexpr int OUT_ = 32;

constexpr int NB = 64;      // blocks: 2 batch rows each
constexpr int NT = 1024;    // threads: 16 waves = 64 sixteen-lane groups

// Single dispatch, no workspace, no cross-block sync, no memset.
// Block = 2 batch rows. 16-lane group G streams gate rows u = G + 64*j
// (768 useful rows/dir: i,g,o; f-gate dead since c=0), 6 rows in flight,
// shuffle-reduces batched (12 independent chains) to hide ds_bpermute latency.
__global__ __launch_bounds__(NT) void bilstm_solo(
    const int*   __restrict__ inputs,
    const float* __restrict__ weight,
    const float* __restrict__ Wxf, const float* __restrict__ bxf, const float* __restrict__ bhf,
    const float* __restrict__ Wxb, const float* __restrict__ bxb, const float* __restrict__ bhb,
    const float* __restrict__ Why, const float* __restrict__ by,
    float*       __restrict__ out)
{
    __shared__ float gd[2][2][3][HID_];              // [b][dir][gate i/g/o][h] 24 KB
    __shared__ __align__(16) float hvc[2][2][HID_];  // [b][dir][h] 8 KB
    __shared__ float lg[2][OUT_];

    const int blk  = blockIdx.x;
    const int tid  = threadIdx.x;
    const int b0   = 2 * blk;
    const int wave = tid >> 6;
    const int lane = tid & 63;
    const int l16  = lane & 15;
    const int G    = tid >> 4;          // 16-lane group id, 0..63

    // ---- stream gate rows for both directions; x held in registers
    #pragma unroll
    for (int dir = 0; dir < 2; ++dir) {
        const float* W   = dir ? Wxb : Wxf;
        const int    pos = dir ? 0 : (S_ - 1);
        const int tA = inputs[(size_t)b0 * S_ + pos];
        const int tB = inputs[(size_t)(b0 + 1) * S_ + pos];
        const float4* xAp = reinterpret_cast<const float4*>(weight + (size_t)tA * EMB_);
        const float4* xBp = reinterpret_cast<const float4*>(weight + (size_t)tB * EMB_);
        const float4 xA0 = xAp[2 * l16], xA1 = xAp[2 * l16 + 1];
        const float4 xB0 = xBp[2 * l16], xB1 = xBp[2 * l16 + 1];

        #pragma unroll
        for (int batch = 0; batch < 2; ++batch) {
            float4 a[6], c[6];
            #pragma unroll
            for (int jj = 0; jj < 6; ++jj) {
                const int u    = G + 64 * (batch * 6 + jj);   // 0..767
                const int gs   = u >> 8;                      // 0:i 1:g 2:o
                const int h    = u & 255;
                const int grow = (gs == 0) ? 0 : (gs + 1);    // rows i->0, g->2, o->3
                const float4* r = reinterpret_cast<const float4*>(
                    W + ((size_t)grow * HID_ + h) * EMB_);
                a[jj] = r[2 * l16];
                c[jj] = r[2 * l16 + 1];
            }
            float p0[6], p1[6];
            #pragma unroll
            for (int jj = 0; jj < 6; ++jj) {
                p0[jj] = a[jj].x * xA0.x + a[jj].y * xA0.y + a[jj].z * xA0.z + a[jj].w * xA0.w
                       + c[jj].x * xA1.x + c[jj].y * xA1.y + c[jj].z * xA1.z + c[jj].w * xA1.w;
                p1[jj] = a[jj].x * xB0.x + a[jj].y * xB0.y + a[jj].z * xB0.z + a[jj].w * xB0.w
                       + c[jj].x * xB1.x + c[jj].y * xB1.y + c[jj].z * xB1.z + c[jj].w * xB1.w;
            }
            // 12 independent 4-step reduce chains (latency overlapped)
            #pragma unroll
            for (int st = 1; st <= 8; st <<= 1) {
                #pragma unroll
                for (int jj = 0; jj < 6; ++jj) {
                    p0[jj] += __shfl_xor(p0[jj], st);
                    p1[jj] += __shfl_xor(p1[jj], st);
                }
            }
            if (l16 == 0) {
                #pragma unroll
                for (int jj = 0; jj < 6; ++jj) {
                    const int u  = G + 64 * (batch * 6 + jj);
                    const int gs = u >> 8;
                    const int h  = u & 255;
                    gd[0][dir][gs][h] = p0[jj];
                    gd[1][dir][gs][h] = p1[jj];
                }
            }
        }
    }
    __syncthreads();

    // ---- gate math: tid = (b<<9)|(dir<<8)|h  (exactly 1024 work items)
    {
        const int b   = tid >> 9;
        const int dir = (tid >> 8) & 1;
        const int h   = tid & 255;
        const float* bx = dir ? bxb : bxf;
        const float* bh = dir ? bhb : bhf;
        const float gi = gd[b][dir][0][h] + bx[h]            + bh[h];
        const float gg = gd[b][dir][1][h] + bx[2 * HID_ + h] + bh[2 * HID_ + h];
        const float go = gd[b][dir][2][h] + bx[3 * HID_ + h] + bh[3 * HID_ + h];
        const float si = 1.0f / (1.0f + expf(-gi));
        const float so = 1.0f / (1.0f + expf(-go));
        hvc[b][dir][h] = so * tanhf(si * tanhf(gg));
    }
    __syncthreads();

    // ---- logits: wave w -> (b = w&1, o = (w>>1) + 8*i), 64-lane dots
    {
        const int b  = wave & 1;
        const int ob = wave >> 1;
        #pragma unroll
        for (int i = 0; i < 4; ++i) {
            const int o = ob + 8 * i;
            const float4 wv = reinterpret_cast<const float4*>(Why + (size_t)o * HID_)[lane];
            const float4 h0 = *reinterpret_cast<const float4*>(&hvc[b][0][4 * lane]);
            const float4 h1 = *reinterpret_cast<const float4*>(&hvc[b][1][4 * lane]);
            float p = wv.x * (h0.x + h1.x) + wv.y * (h0.y + h1.y)
                    + wv.z * (h0.z + h1.z) + wv.w * (h0.w + h1.w);
            #pragma unroll
            for (int off = 32; off; off >>= 1) p += __shfl_xor(p, off);
            if (lane == 0) lg[b][o] = p + by[o];
        }
    }
    __syncthreads();

    // ---- two 32-wide log-softmaxes in wave 0 (lanes 0-31: b0, 32-63: b1)
    if (tid < 64) {
        const int b = tid >> 5;
        const int o = tid & 31;
        const float v = lg[b][o];
        float m = v;
        #pragma unroll
        for (int off = 16; off; off >>= 1) m = fmaxf(m, __shfl_xor(m, off));
        float s = expf(v - m);
        #pragma unroll
        for (int off = 16; off; off >>= 1) s += __shfl_xor(s, off);
        out[(size_t)(b0 + b) * OUT_ + o] = v - m - logf(s);
    }
}

extern "C" void kernel_launch(void* const* d_in, const int* in_sizes, int n_in,
                              void* d_out, int out_size, void* d_ws, size_t ws_size,
                              hipStream_t stream) {
    // setup_inputs() order:
    // 0 inputs [B,S] int32      1 weight [VOCAB,EMB] f32
    // 2 Wxf [1024,128]  3 bxf [1024]  4 Whf (dead)  5 bhf [1024]
    // 6 Wxb [1024,128]  7 bxb [1024]  8 Whb (dead)  9 bhb [1024]
    // 10 Why [32,256]   11 by [32]
    const int*   inputs = (const int*)  d_in[0];
    const float* weight = (const float*)d_in[1];
    const float* Wxf    = (const float*)d_in[2];
    const float* bxf    = (const float*)d_in[3];
    const float* bhf    = (const float*)d_in[5];
    const float* Wxb    = (const float*)d_in[6];
    const float* bxb    = (const float*)d_in[7];
    const float* bhb    = (const float*)d_in[9];
    const float* Why    = (const float*)d_in[10];
    const float* by     = (const float*)d_in[11];
    float* out = (float*)d_out;

    // Single dispatch. No workspace, no memset, no cross-block sync.
    bilstm_solo<<<NB, NT, 0, stream>>>(inputs, weight,
                                       Wxf, bxf, bhf,
                                       Wxb, bxb, bhb,
                                       Why, by, out);
}

// Round 11
// 15.065 us; speedup vs baseline: 2.7780x; 1.3235x over previous
//
#include <hip/hip_runtime.h>
#include <math.h>

// Problem constants (from the reference file)
constexpr int B_   = 128;
constexpr int S_   = 2048;
constexpr int EMB_ = 128;
constexpr int HID_ = 256;
constexpr int OUT_ = 32;

constexpr int HT   = 8;         // h per block (proven R3 geometry)
constexpr int BH   = 64;        // b per block (half the batch)
constexpr int PADK = EMB_ + 4;  // 132: 16B-aligned rows, stride%32==4 -> conflict-free b128

// ws layout: hy[2][B][HID] floats at offset 0 (256 KB). Fully rewritten every call.

// ---------------------------------------------------------------------------
// Kernel 1 (R3 verbatim): tiled weight-stationary gates GEMM + activations.
// grid = 2 dirs x 32 h-tiles x 2 b-halves = 128 blocks, 512 threads.
__global__ __launch_bounds__(512) void gates_gemm(
    const int*   __restrict__ inputs,
    const float* __restrict__ weight,
    const float* __restrict__ Wxf, const float* __restrict__ bxf, const float* __restrict__ bhf,
    const float* __restrict__ Wxb, const float* __restrict__ bxb, const float* __restrict__ bhb,
    float*       __restrict__ hy_ws)            // [2][B][HID]
{
    __shared__ __align__(16) float Xs[BH][PADK];      // 33.8 KB
    __shared__ __align__(16) float Ws[3][HT][PADK];   // 12.7 KB
    __shared__ int toks[BH];

    const int blk   = blockIdx.x;
    const int dir   = blk >> 6;          // 64 blocks per direction
    const int ht    = (blk & 63) >> 1;   // 0..31
    const int bhalf = blk & 1;
    const int h0    = ht * HT;
    const int tid   = threadIdx.x;

    if (tid < BH)
        toks[tid] = inputs[(size_t)(bhalf * BH + tid) * S_ + (dir ? 0 : (S_ - 1))];
    __syncthreads();

    // stage X: 64 rows x 32 float4 = 2048 float4, 4 passes of 512
    #pragma unroll
    for (int p = 0; p < 4; ++p) {
        const int idx = p * 512 + tid;
        const int bl  = idx >> 5;
        const int j   = idx & 31;
        const float4 v = reinterpret_cast<const float4*>(weight + (size_t)toks[bl] * EMB_)[j];
        *reinterpret_cast<float4*>(&Xs[bl][4 * j]) = v;
    }
    // stage W: 3 gates x 8 rows x 32 float4 (4KB contiguous per gate chunk)
    {
        const float* Wx = dir ? Wxb : Wxf;
        for (int idx = tid; idx < 3 * HT * 32; idx += 512) {
            const int g   = idx >> 8;
            const int rem = idx & 255;
            const int hl  = rem >> 5;
            const int j   = rem & 31;
            const int grow = (g == 0) ? 0 : ((g == 1) ? 2 : 3);  // i, g, o rows
            const float4 v = reinterpret_cast<const float4*>(
                Wx + (size_t)(grow * HID_ + h0 + hl) * EMB_)[j];
            *reinterpret_cast<float4*>(&Ws[g][hl][4 * j]) = v;
        }
    }
    __syncthreads();

    // compute: thread = (hl = tid&7, bg = tid>>3) -> one (b, h) pair.
    // W reads broadcast among the 8 lanes sharing hl; X reads broadcast among
    // the 8 lanes sharing bg; PADK keeps distinct rows on distinct banks.
    const int hl = tid & (HT - 1);
    const int bg = tid >> 3;
    const int b  = bhalf * BH + bg;
    const int h  = h0 + hl;

    const float* bx = dir ? bxb : bxf;
    const float* bh = dir ? bhb : bhf;
    float gi = bx[h]            + bh[h];
    float gg = bx[2 * HID_ + h] + bh[2 * HID_ + h];
    float go = bx[3 * HID_ + h] + bh[3 * HID_ + h];

    #pragma unroll 8
    for (int k4 = 0; k4 < EMB_ / 4; ++k4) {
        const float4 x  = *reinterpret_cast<const float4*>(&Xs[bg][4 * k4]);
        const float4 wi = *reinterpret_cast<const float4*>(&Ws[0][hl][4 * k4]);
        const float4 wg = *reinterpret_cast<const float4*>(&Ws[1][hl][4 * k4]);
        const float4 wo = *reinterpret_cast<const float4*>(&Ws[2][hl][4 * k4]);
        gi = fmaf(x.x, wi.x, fmaf(x.y, wi.y, fmaf(x.z, wi.z, fmaf(x.w, wi.w, gi))));
        gg = fmaf(x.x, wg.x, fmaf(x.y, wg.y, fmaf(x.z, wg.z, fmaf(x.w, wg.w, gg))));
        go = fmaf(x.x, wo.x, fmaf(x.y, wo.y, fmaf(x.z, wo.z, fmaf(x.w, wo.w, go))));
    }

    const float si = 1.0f / (1.0f + expf(-gi));
    const float so = 1.0f / (1.0f + expf(-go));
    hy_ws[((size_t)dir * B_ + b) * HID_ + h] = so * tanhf(si * tanhf(gg));
}

// ---------------------------------------------------------------------------
// Kernel 2 (leaner): combine directions, logits, log-softmax.
// 128 blocks (one per b), 256 threads = 4 waves; wave w owns outputs
// o = w + 4*i (8 rows), each a 64-lane float4 dot + shuffle reduce.
__global__ __launch_bounds__(256) void epilogue(
    const float* __restrict__ hy_ws,
    const float* __restrict__ Why,
    const float* __restrict__ by,
    float*       __restrict__ out)
{
    __shared__ __align__(16) float hs[HID_];
    __shared__ float lg[OUT_];

    const int b   = blockIdx.x;
    const int tid = threadIdx.x;

    if (tid < HID_ / 4) {   // 64 threads: hs = hy_f + hy_b (two 1KB rows)
        const float4 f = reinterpret_cast<const float4*>(hy_ws + (size_t)b * HID_)[tid];
        const float4 r = reinterpret_cast<const float4*>(hy_ws + ((size_t)B_ + b) * HID_)[tid];
        *reinterpret_cast<float4*>(&hs[4 * tid]) =
            make_float4(f.x + r.x, f.y + r.y, f.z + r.z, f.w + r.w);
    }
    __syncthreads();

    const int w    = tid >> 6;     // wave 0..3
    const int lane = tid & 63;
    const float4 hv = *reinterpret_cast<const float4*>(&hs[4 * lane]);
    #pragma unroll
    for (int i = 0; i < OUT_ / 4; ++i) {       // 8 rows per wave
        const int o = w + 4 * i;
        const float4 wv = reinterpret_cast<const float4*>(Why + (size_t)o * HID_)[lane];
        float p = fmaf(hv.x, wv.x, fmaf(hv.y, wv.y, fmaf(hv.z, wv.z, hv.w * wv.w)));
        #pragma unroll
        for (int off = 32; off; off >>= 1) p += __shfl_xor(p, off);
        if (lane == 0) lg[o] = p + by[o];
    }
    __syncthreads();

    if (tid < OUT_) {               // 32-wide log-softmax, lanes 0..31
        const float v = lg[tid];
        float m = v;
        #pragma unroll
        for (int off = 16; off; off >>= 1) m = fmaxf(m, __shfl_xor(m, off));
        float s = expf(v - m);
        #pragma unroll
        for (int off = 16; off; off >>= 1) s += __shfl_xor(s, off);
        out[(size_t)b * OUT_ + tid] = v - m - logf(s);
    }
}

extern "C" void kernel_launch(void* const* d_in, const int* in_sizes, int n_in,
                              void* d_out, int out_size, void* d_ws, size_t ws_size,
                              hipStream_t stream) {
    // setup_inputs() order:
    // 0 inputs [B,S] int32      1 weight [VOCAB,EMB] f32
    // 2 Wxf [1024,128]  3 bxf [1024]  4 Whf (dead)  5 bhf [1024]
    // 6 Wxb [1024,128]  7 bxb [1024]  8 Whb (dead)  9 bhb [1024]
    // 10 Why [32,256]   11 by [32]
    const int*   inputs = (const int*)  d_in[0];
    const float* weight = (const float*)d_in[1];
    const float* Wxf    = (const float*)d_in[2];
    const float* bxf    = (const float*)d_in[3];
    const float* bhf    = (const float*)d_in[5];
    const float* Wxb    = (const float*)d_in[6];
    const float* bxb    = (const float*)d_in[7];
    const float* bhb    = (const float*)d_in[9];
    const float* Why    = (const float*)d_in[10];
    const float* by     = (const float*)d_in[11];
    float* out = (float*)d_out;

    float* hy_ws = (float*)d_ws;   // [2][B][HID] = 256 KB

    gates_gemm<<<128, 512, 0, stream>>>(inputs, weight,
                                        Wxf, bxf, bhf,
                                        Wxb, bxb, bhb, hy_ws);
    epilogue<<<B_, 256, 0, stream>>>(hy_ws, Why, by, out);
}